// Round 1
// baseline (722.435 us; speedup 1.0000x reference)
//
#include <hip/hip_runtime.h>
#include <hip/hip_fp16.h>
#include <math.h>

#define N_NODES 100000
#define N_BASE  5000
#define N_EDGES 3200000
#define NBKT    391       // dest buckets of 256 nodes; also = ceil(E/8192) edge blocks
#define CAPB    9472      // csr slots per bucket (mean 8184, sigma 90 -> +14 sigma)

__device__ inline unsigned pkh(float a, float b) {
    return (unsigned)__half_as_ushort(__float2half_rn(a)) |
           ((unsigned)__half_as_ushort(__float2half_rn(b)) << 16);
}

// ---------------------------------------------------------------------------
// k_initg: gcur[b] = b*CAPB, bins = 0
// ---------------------------------------------------------------------------
__global__ __launch_bounds__(512) void k_initg(int* __restrict__ gcur, float* __restrict__ bins) {
    int t = threadIdx.x;
    if (t < NBKT) gcur[t] = t * CAPB;
    if (t < 64) bins[t] = 0.0f;
}

// ---------------------------------------------------------------------------
// k_bucket (phase A): 391 blocks x 8192 edges. LDS histogram over 391 dest
// buckets -> LDS scan -> one global chunk reservation per (block,bucket) ->
// direct chunked stores of packed (d&255)<<17 | src.
// ---------------------------------------------------------------------------
__global__ __launch_bounds__(256) void k_bucket(const int* __restrict__ row, const int* __restrict__ col,
                                                int* __restrict__ gcur, unsigned* __restrict__ csr) {
    __shared__ int hist[NBKT], gbase[NBKT], cur[NBKT];
    __shared__ int sc[512];
    int t = threadIdx.x;
    int e0 = blockIdx.x * 8192;
    int cnt = (N_EDGES - e0 < 8192) ? (N_EDGES - e0) : 8192;
    for (int k = t; k < NBKT; k += 256) hist[k] = 0;
    __syncthreads();
    for (int j = t; j < cnt; j += 256) atomicAdd(&hist[col[e0 + j] >> 8], 1);
    __syncthreads();
    // inclusive Hillis scan over 512 slots, 2 per thread
    sc[t] = (t < NBKT) ? hist[t] : 0;
    sc[t + 256] = (t + 256 < NBKT) ? hist[t + 256] : 0;
    __syncthreads();
    for (int off = 1; off < 512; off <<= 1) {
        int v0 = (t >= off) ? sc[t - off] : 0;
        int v1 = sc[t + 256 - off];          // t+256-off >= 0 since off <= 256
        __syncthreads();
        sc[t] += v0;
        sc[t + 256] += v1;
        __syncthreads();
    }
    for (int s = t; s < NBKT; s += 256) {
        cur[s] = sc[s] - hist[s];            // local exclusive offset
        gbase[s] = (hist[s] > 0) ? atomicAdd(&gcur[s], hist[s]) : 0;
    }
    __syncthreads();
    for (int j = t; j < cnt; j += 256) {
        int d = col[e0 + j];
        int s = row[e0 + j];
        int b = d >> 8;
        int slot = atomicAdd(&cur[b], 1);
        int local = slot - (sc[b] - hist[b]);
        csr[gbase[b] + local] = ((unsigned)(d & 255) << 17) | (unsigned)s;
    }
}

// ---------------------------------------------------------------------------
// k_sort (phase B): one block per bucket. LDS counting sort of <= CAPB edges
// by local dest; coalesced write-back of pure-src csr into the bucket's own
// window; emits rs/re (exact runs) and dinv (true degree).
// ---------------------------------------------------------------------------
__global__ __launch_bounds__(256) void k_sort(const int* __restrict__ gcur, unsigned* __restrict__ csr,
                                              int* __restrict__ rs, int* __restrict__ re,
                                              float* __restrict__ dinv) {
    __shared__ unsigned stage[CAPB];
    __shared__ int hist[256], offs[256], cur[256];
    int t = threadIdx.x, b = blockIdx.x;
    int base = b * CAPB;
    int cnt = gcur[b] - base;
    hist[t] = 0;
    for (int j = t; j < cnt; j += 256) stage[j] = csr[base + j];
    __syncthreads();
    for (int j = t; j < cnt; j += 256) atomicAdd(&hist[stage[j] >> 17], 1);
    __syncthreads();
    offs[t] = hist[t];
    __syncthreads();
    for (int off = 1; off < 256; off <<= 1) {
        int v = (t >= off) ? offs[t - off] : 0;
        __syncthreads();
        offs[t] += v;
        __syncthreads();
    }
    int excl = offs[t] - hist[t];
    cur[t] = excl;
    int node = b * 256 + t;
    if (node < N_NODES) {
        rs[node] = base + excl;
        re[node] = base + excl + hist[t];
        dinv[node] = rsqrtf((float)(hist[t] + 1));   // +1 self loop
    }
    __syncthreads();
    for (int j = t; j < cnt; j += 256) {
        unsigned p = stage[j];
        int slot = atomicAdd(&cur[p >> 17], 1);
        csr[base + slot] = p & 0x1FFFFu;             // pure src
    }
}

// ---------------------------------------------------------------------------
// k_ab_h: bb = [x1 | tile(x2)] @ W4^T + b4  (float4 stores, f32)
//         h0 = dinv * (Wg @ [relu(x1@W1^T+b1) | bb])   ** fp16 stores **
//         bins += W3[15:34].bb   (iteration-invariant output part)
// h rows are 16 halfs = 32 B: the full h working set is 3.2 MB and fits a
// per-XCD L2 (4 MB), converting gather LLC misses into L2 hits.
// ---------------------------------------------------------------------------
__global__ __launch_bounds__(256) void k_ab_h(const float* __restrict__ x1, const float* __restrict__ x2,
                                              const float* __restrict__ W1, const float* __restrict__ b1,
                                              const float* __restrict__ W4, const float* __restrict__ b4,
                                              const float* __restrict__ Wg, const float* __restrict__ W3,
                                              const float* __restrict__ dinv,
                                              float* __restrict__ bb, __half* __restrict__ h0,
                                              float* __restrict__ bins) {
    __shared__ float sW1[225], sb1[15], sW4[361], sb4[19], sWg[510], sW3b[19];
    for (int t = threadIdx.x; t < 225; t += 256) sW1[t] = W1[t];
    for (int t = threadIdx.x; t < 361; t += 256) sW4[t] = W4[t];
    for (int t = threadIdx.x; t < 510; t += 256) sWg[t] = Wg[t];
    if (threadIdx.x < 15) sb1[threadIdx.x] = b1[threadIdx.x];
    if (threadIdx.x < 19) { sb4[threadIdx.x] = b4[threadIdx.x]; sW3b[threadIdx.x] = W3[15 + threadIdx.x]; }
    __syncthreads();
    int i = blockIdx.x * 256 + threadIdx.x;
    bool valid = i < N_NODES;
    int ii = valid ? i : 0;
    float x[15];
#pragma unroll
    for (int k = 0; k < 15; k++) x[k] = x1[(size_t)ii * 15 + k];
    float xt[4];
    int ib = ii % N_BASE;
#pragma unroll
    for (int k = 0; k < 4; k++) xt[k] = x2[(size_t)ib * 4 + k];
    float in[34];
    float bp = 0.0f;
#pragma unroll
    for (int o = 0; o < 19; o++) {
        float s = sb4[o];
#pragma unroll
        for (int k = 0; k < 15; k++) s += x[k] * sW4[o * 19 + k];
#pragma unroll
        for (int k = 0; k < 4; k++) s += xt[k] * sW4[o * 19 + 15 + k];
        in[15 + o] = s;
        bp += s * sW3b[o];
    }
#pragma unroll
    for (int o = 0; o < 15; o++) {
        float s = sb1[o];
#pragma unroll
        for (int k = 0; k < 15; k++) s += x[k] * sW1[o * 15 + k];
        in[o] = fmaxf(s, 0.0f);
    }
    float dn = dinv[ii];
    if (valid) {
        float4* bbp = (float4*)(bb + (size_t)ii * 20);
        bbp[0] = make_float4(in[15], in[16], in[17], in[18]);
        bbp[1] = make_float4(in[19], in[20], in[21], in[22]);
        bbp[2] = make_float4(in[23], in[24], in[25], in[26]);
        bbp[3] = make_float4(in[27], in[28], in[29], in[30]);
        bbp[4] = make_float4(in[31], in[32], in[33], 0.0f);   // [19] pad, never consumed
        float hv[15];
#pragma unroll
        for (int o = 0; o < 15; o++) {
            float s = 0.0f;
#pragma unroll
            for (int k = 0; k < 34; k++) s += in[k] * sWg[o * 34 + k];
            hv[o] = s * dn;
        }
        unsigned hu[8];
#pragma unroll
        for (int k = 0; k < 7; k++) hu[k] = pkh(hv[2 * k], hv[2 * k + 1]);
        hu[7] = pkh(hv[14], 0.0f);                            // ch 15 pad, never consumed
        uint4* hp = (uint4*)(h0 + (size_t)ii * 16);
        hp[0] = make_uint4(hu[0], hu[1], hu[2], hu[3]);
        hp[1] = make_uint4(hu[4], hu[5], hu[6], hu[7]);
    }
    float val = valid ? bp : 0.0f;
#pragma unroll
    for (int off = 32; off > 0; off >>= 1) val += __shfl_down(val, off, 64);
    __shared__ float wsum[4];
    if ((threadIdx.x & 63) == 0) wsum[threadIdx.x >> 6] = val;
    __syncthreads();
    if (threadIdx.x == 0) atomicAdd(&bins[blockIdx.x & 63], wsum[0] + wsum[1] + wsum[2] + wsum[3]);
}

// ---------------------------------------------------------------------------
// k_gather: same structure as the f32 version (16 independent predicated
// loads in flight per wave, identical f32 summation order); h rows are now
// fp16 (32 B) so the random gather working set (3.2 MB) fits per-XCD L2 and
// per-edge miss bytes halve. acc += __half2float(tmp) in the same ascending
// order as before -> only numeric delta is the fp16 quantization of h.
// ---------------------------------------------------------------------------
__global__ __launch_bounds__(1024) void k_gather(const int* __restrict__ rs, const int* __restrict__ re,
                                                 const unsigned* __restrict__ csr,
                                                 const __half* __restrict__ h_in,
                                                 const float* __restrict__ dinv,
                                                 const float* __restrict__ bb,
                                                 const float* __restrict__ Wg,
                                                 const float* __restrict__ bg,
                                                 const float* __restrict__ W3,
                                                 __half* __restrict__ h_out,
                                                 float* __restrict__ bins, int last) {
    __shared__ float sWg[544], sbg[16], sW3[16];
    __shared__ float ws2[16];
    int t = threadIdx.x;
    for (int k = t; k < 544; k += 1024) sWg[k] = (k < 510) ? Wg[k] : 0.0f;
    if (t < 16) { sbg[t] = (t < 15) ? bg[t] : 0.0f; sW3[t] = (t < 15) ? W3[t] : 0.0f; }
    __syncthreads();
    int node = blockIdx.x * 16 + (t >> 6);
    int lane = t & 63, ch = lane & 15, q = lane >> 4;
    int start = rs[node];
    int deg = re[node] - start;
    float hs = __half2float(h_in[(size_t)node * 16 + ch]);   // self row, hoisted for overlap
    float acc = 0.0f;
    for (int base = 0; base < deg; base += 64) {
        int rem = deg - base;
        unsigned ce = 0;
        if (lane < rem) ce = csr[start + base + lane];
        int lim = rem < 64 ? rem : 64;
        float tmp[16];
#pragma unroll
        for (int i = 0; i < 16; i++) {
            int e0 = q + 4 * i;
            unsigned p = __shfl(ce, e0, 64);
            tmp[i] = (e0 < lim) ? __half2float(h_in[(size_t)(p & 0x1FFFFu) * 16 + ch]) : 0.0f;
        }
#pragma unroll
        for (int i = 0; i < 16; i++) acc += tmp[i];
    }
    acc += __shfl_xor(acc, 16, 64);
    acc += __shfl_xor(acc, 32, 64);
    float dn = dinv[node];
    float aval = fmaxf(dn * (hs + acc) + sbg[ch], 0.0f);   // a[ch]; ch==15 -> 0
    if (!last) {
        float ink[15];
#pragma unroll
        for (int k = 0; k < 15; k++) ink[k] = __shfl(aval, k, 64);
        const float4* bp4 = (const float4*)(bb + (size_t)node * 20);
        float4 q0 = bp4[0], q1 = bp4[1], q2 = bp4[2], q3 = bp4[3], q4 = bp4[4];
        float bv[19] = {q0.x, q0.y, q0.z, q0.w, q1.x, q1.y, q1.z, q1.w,
                        q2.x, q2.y, q2.z, q2.w, q3.x, q3.y, q3.z, q3.w,
                        q4.x, q4.y, q4.z};
        float s = 0.0f;
#pragma unroll
        for (int k = 0; k < 15; k++) s += ink[k] * sWg[ch * 34 + k];
#pragma unroll
        for (int k = 0; k < 19; k++) s += bv[k] * sWg[ch * 34 + 15 + k];
        if (q == 0) h_out[(size_t)node * 16 + ch] = __float2half_rn(s * dn);  // ch==15: sWg pad -> 0
    } else {
        float c = aval * sW3[ch];
        c += __shfl_xor(c, 8, 64);
        c += __shfl_xor(c, 4, 64);
        c += __shfl_xor(c, 2, 64);
        c += __shfl_xor(c, 1, 64);
        if (lane == 0) ws2[t >> 6] = c;
        __syncthreads();
        if (t == 0) {
            float s = 0.0f;
#pragma unroll
            for (int k = 0; k < 16; k++) s += ws2[k];
            atomicAdd(&bins[blockIdx.x & 63], s);
        }
    }
}

__global__ void k_finalize(const float* __restrict__ bins, const float* __restrict__ b3,
                           float* __restrict__ out) {
    float s = 0.0f;
    for (int k = 0; k < 64; k++) s += bins[k];
    out[0] = tanhf(s * (1.0f / (float)N_NODES) + b3[0]);
}

// ---------------------------------------------------------------------------
extern "C" void kernel_launch(void* const* d_in, const int* in_sizes, int n_in,
                              void* d_out, int out_size, void* d_ws, size_t ws_size,
                              hipStream_t stream) {
    const float* x1 = (const float*)d_in[0];
    const float* x2 = (const float*)d_in[1];
    const int* edges = (const int*)d_in[2];
    const float* W1 = (const float*)d_in[3];
    const float* b1 = (const float*)d_in[4];
    const float* Wg = (const float*)d_in[5];
    const float* bg = (const float*)d_in[6];
    const float* W3 = (const float*)d_in[7];
    const float* b3 = (const float*)d_in[8];
    const float* W4 = (const float*)d_in[9];
    const float* b4 = (const float*)d_in[10];

    const int* row = edges;             // edges[0]
    const int* col = edges + N_EDGES;   // edges[1]

    // workspace layout — ~30 MB (h0/h1 now fp16: 3.2 MB each).
    char* ws = (char*)d_ws;
    unsigned* csr  = (unsigned*)ws;                              // NBKT*CAPB  (14.81 MB)
    float*    bb   = (float*)(csr + (size_t)NBKT * CAPB);        // N*20 f32   (8.0 MB)
    __half*   h0   = (__half*)(bb + (size_t)N_NODES * 20);       // N*16 fp16  (3.2 MB)
    __half*   h1   = h0 + (size_t)N_NODES * 16;                  // N*16 fp16  (3.2 MB)
    float*    dinv = (float*)(h1 + (size_t)N_NODES * 16);        // N
    int*      rs   = (int*)(dinv + N_NODES);                     // N
    int*      re   = rs + N_NODES;                               // N
    int*      gcur = re + N_NODES;                               // NBKT
    float*    bins = (float*)(gcur + NBKT);                      // 64

    int gN = (N_NODES + 255) / 256;                              // 391
    int gE = (N_EDGES + 8191) / 8192;                            // 391

    k_initg<<<1, 512, 0, stream>>>(gcur, bins);
    k_bucket<<<gE, 256, 0, stream>>>(row, col, gcur, csr);
    k_sort<<<NBKT, 256, 0, stream>>>(gcur, csr, rs, re, dinv);
    k_ab_h<<<gN, 256, 0, stream>>>(x1, x2, W1, b1, W4, b4, Wg, W3, dinv, bb, h0, bins);
    for (int t = 0; t < 5; t++) {
        const __half* hi = (t & 1) ? h1 : h0;
        __half* ho = (t & 1) ? h0 : h1;
        k_gather<<<N_NODES / 16, 1024, 0, stream>>>(rs, re, csr, hi, dinv, bb, Wg, bg, W3,
                                                    ho, bins, t == 4 ? 1 : 0);
    }
    k_finalize<<<1, 1, 0, stream>>>(bins, b3, (float*)d_out);
}

// Round 2
// 459.809 us; speedup vs baseline: 1.5712x; 1.5712x over previous
//
#include <hip/hip_runtime.h>
#include <hip/hip_fp16.h>
#include <math.h>

#define N_NODES 100000
#define N_BASE  5000
#define N_EDGES 3200000
#define NBKT    391       // dest buckets of 256 nodes; also = ceil(E/8192) edge blocks
#define CAPB    9472      // csr slots per bucket (mean 8184, sigma 90 -> +14 sigma)

__device__ inline unsigned pkh(float a, float b) {
    return (unsigned)__half_as_ushort(__float2half_rn(a)) |
           ((unsigned)__half_as_ushort(__float2half_rn(b)) << 16);
}

// ---------------------------------------------------------------------------
// k_initg: gcur[b] = b*CAPB, bins = 0
// ---------------------------------------------------------------------------
__global__ __launch_bounds__(512) void k_initg(int* __restrict__ gcur, float* __restrict__ bins) {
    int t = threadIdx.x;
    if (t < NBKT) gcur[t] = t * CAPB;
    if (t < 64) bins[t] = 0.0f;
}

// ---------------------------------------------------------------------------
// k_bucket (phase A): 391 blocks x 8192 edges. LDS histogram over 391 dest
// buckets -> LDS scan -> one global chunk reservation per (block,bucket) ->
// direct chunked stores of packed (d&255)<<17 | src.
// ---------------------------------------------------------------------------
__global__ __launch_bounds__(256) void k_bucket(const int* __restrict__ row, const int* __restrict__ col,
                                                int* __restrict__ gcur, unsigned* __restrict__ csr) {
    __shared__ int hist[NBKT], gbase[NBKT], cur[NBKT];
    __shared__ int sc[512];
    int t = threadIdx.x;
    int e0 = blockIdx.x * 8192;
    int cnt = (N_EDGES - e0 < 8192) ? (N_EDGES - e0) : 8192;
    for (int k = t; k < NBKT; k += 256) hist[k] = 0;
    __syncthreads();
    for (int j = t; j < cnt; j += 256) atomicAdd(&hist[col[e0 + j] >> 8], 1);
    __syncthreads();
    // inclusive Hillis scan over 512 slots, 2 per thread
    sc[t] = (t < NBKT) ? hist[t] : 0;
    sc[t + 256] = (t + 256 < NBKT) ? hist[t + 256] : 0;
    __syncthreads();
    for (int off = 1; off < 512; off <<= 1) {
        int v0 = (t >= off) ? sc[t - off] : 0;
        int v1 = sc[t + 256 - off];          // t+256-off >= 0 since off <= 256
        __syncthreads();
        sc[t] += v0;
        sc[t + 256] += v1;
        __syncthreads();
    }
    for (int s = t; s < NBKT; s += 256) {
        cur[s] = sc[s] - hist[s];            // local exclusive offset
        gbase[s] = (hist[s] > 0) ? atomicAdd(&gcur[s], hist[s]) : 0;
    }
    __syncthreads();
    for (int j = t; j < cnt; j += 256) {
        int d = col[e0 + j];
        int s = row[e0 + j];
        int b = d >> 8;
        int slot = atomicAdd(&cur[b], 1);
        int local = slot - (sc[b] - hist[b]);
        csr[gbase[b] + local] = ((unsigned)(d & 255) << 17) | (unsigned)s;
    }
}

// ---------------------------------------------------------------------------
// k_sort (phase B): one block per bucket. LDS counting sort of <= CAPB edges
// by local dest; coalesced write-back of pure-src csr into the bucket's own
// window; emits rs/re (exact runs) and dinv (true degree).
// ---------------------------------------------------------------------------
__global__ __launch_bounds__(256) void k_sort(const int* __restrict__ gcur, unsigned* __restrict__ csr,
                                              int* __restrict__ rs, int* __restrict__ re,
                                              float* __restrict__ dinv) {
    __shared__ unsigned stage[CAPB];
    __shared__ int hist[256], offs[256], cur[256];
    int t = threadIdx.x, b = blockIdx.x;
    int base = b * CAPB;
    int cnt = gcur[b] - base;
    hist[t] = 0;
    for (int j = t; j < cnt; j += 256) stage[j] = csr[base + j];
    __syncthreads();
    for (int j = t; j < cnt; j += 256) atomicAdd(&hist[stage[j] >> 17], 1);
    __syncthreads();
    offs[t] = hist[t];
    __syncthreads();
    for (int off = 1; off < 256; off <<= 1) {
        int v = (t >= off) ? offs[t - off] : 0;
        __syncthreads();
        offs[t] += v;
        __syncthreads();
    }
    int excl = offs[t] - hist[t];
    cur[t] = excl;
    int node = b * 256 + t;
    if (node < N_NODES) {
        rs[node] = base + excl;
        re[node] = base + excl + hist[t];
        dinv[node] = rsqrtf((float)(hist[t] + 1));   // +1 self loop
    }
    __syncthreads();
    for (int j = t; j < cnt; j += 256) {
        unsigned p = stage[j];
        int slot = atomicAdd(&cur[p >> 17], 1);
        csr[base + slot] = p & 0x1FFFFu;             // pure src
    }
}

// ---------------------------------------------------------------------------
// k_ab_h: bb = [x1 | tile(x2)] @ W4^T + b4  (float4 stores, f32)
//         h0 = dinv * (Wg @ [relu(x1@W1^T+b1) | bb])   ** fp16 stores **
//         bins += W3[15:34].bb   (iteration-invariant output part)
// h rows are 16 halfs = 32 B: the full h working set is 3.2 MB and fits a
// per-XCD L2 (4 MB) -- round-0 counters confirmed (FETCH 100.5 -> 26.5 MB).
// ---------------------------------------------------------------------------
__global__ __launch_bounds__(256) void k_ab_h(const float* __restrict__ x1, const float* __restrict__ x2,
                                              const float* __restrict__ W1, const float* __restrict__ b1,
                                              const float* __restrict__ W4, const float* __restrict__ b4,
                                              const float* __restrict__ Wg, const float* __restrict__ W3,
                                              const float* __restrict__ dinv,
                                              float* __restrict__ bb, __half* __restrict__ h0,
                                              float* __restrict__ bins) {
    __shared__ float sW1[225], sb1[15], sW4[361], sb4[19], sWg[510], sW3b[19];
    for (int t = threadIdx.x; t < 225; t += 256) sW1[t] = W1[t];
    for (int t = threadIdx.x; t < 361; t += 256) sW4[t] = W4[t];
    for (int t = threadIdx.x; t < 510; t += 256) sWg[t] = Wg[t];
    if (threadIdx.x < 15) sb1[threadIdx.x] = b1[threadIdx.x];
    if (threadIdx.x < 19) { sb4[threadIdx.x] = b4[threadIdx.x]; sW3b[threadIdx.x] = W3[15 + threadIdx.x]; }
    __syncthreads();
    int i = blockIdx.x * 256 + threadIdx.x;
    bool valid = i < N_NODES;
    int ii = valid ? i : 0;
    float x[15];
#pragma unroll
    for (int k = 0; k < 15; k++) x[k] = x1[(size_t)ii * 15 + k];
    float xt[4];
    int ib = ii % N_BASE;
#pragma unroll
    for (int k = 0; k < 4; k++) xt[k] = x2[(size_t)ib * 4 + k];
    float in[34];
    float bp = 0.0f;
#pragma unroll
    for (int o = 0; o < 19; o++) {
        float s = sb4[o];
#pragma unroll
        for (int k = 0; k < 15; k++) s += x[k] * sW4[o * 19 + k];
#pragma unroll
        for (int k = 0; k < 4; k++) s += xt[k] * sW4[o * 19 + 15 + k];
        in[15 + o] = s;
        bp += s * sW3b[o];
    }
#pragma unroll
    for (int o = 0; o < 15; o++) {
        float s = sb1[o];
#pragma unroll
        for (int k = 0; k < 15; k++) s += x[k] * sW1[o * 15 + k];
        in[o] = fmaxf(s, 0.0f);
    }
    float dn = dinv[ii];
    if (valid) {
        float4* bbp = (float4*)(bb + (size_t)ii * 20);
        bbp[0] = make_float4(in[15], in[16], in[17], in[18]);
        bbp[1] = make_float4(in[19], in[20], in[21], in[22]);
        bbp[2] = make_float4(in[23], in[24], in[25], in[26]);
        bbp[3] = make_float4(in[27], in[28], in[29], in[30]);
        bbp[4] = make_float4(in[31], in[32], in[33], 0.0f);   // [19] pad, never consumed
        float hv[15];
#pragma unroll
        for (int o = 0; o < 15; o++) {
            float s = 0.0f;
#pragma unroll
            for (int k = 0; k < 34; k++) s += in[k] * sWg[o * 34 + k];
            hv[o] = s * dn;
        }
        unsigned hu[8];
#pragma unroll
        for (int k = 0; k < 7; k++) hu[k] = pkh(hv[2 * k], hv[2 * k + 1]);
        hu[7] = pkh(hv[14], 0.0f);                            // ch 15 pad, always 0
        uint4* hp = (uint4*)(h0 + (size_t)ii * 16);
        hp[0] = make_uint4(hu[0], hu[1], hu[2], hu[3]);
        hp[1] = make_uint4(hu[4], hu[5], hu[6], hu[7]);
    }
    float val = valid ? bp : 0.0f;
#pragma unroll
    for (int off = 32; off > 0; off >>= 1) val += __shfl_down(val, off, 64);
    __shared__ float wsum[4];
    if ((threadIdx.x & 63) == 0) wsum[threadIdx.x >> 6] = val;
    __syncthreads();
    if (threadIdx.x == 0) atomicAdd(&bins[blockIdx.x & 63], wsum[0] + wsum[1] + wsum[2] + wsum[3]);
}

// ---------------------------------------------------------------------------
// k_gather (round 1): fp16 h kept (L2-resident, proven), but gather loads are
// back to DWORD-per-lane: each lane loads one half2 (uint, 2 channels), 8
// lanes cover one 32B row. Per 64-edge batch each lane issues 8 independent
// dword loads (vs 16 in the f32 version, vs 16 ushort loads in round 0 --
// the ushort shape was the regression). Reduction over the 8 p-slots via
// 3 shfl_xor per component; epilogue computes 2 output channels per lane.
// ---------------------------------------------------------------------------
__global__ __launch_bounds__(1024) void k_gather(const int* __restrict__ rs, const int* __restrict__ re,
                                                 const unsigned* __restrict__ csr,
                                                 const __half* __restrict__ h_in,
                                                 const float* __restrict__ dinv,
                                                 const float* __restrict__ bb,
                                                 const float* __restrict__ Wg,
                                                 const float* __restrict__ bg,
                                                 const float* __restrict__ W3,
                                                 __half* __restrict__ h_out,
                                                 float* __restrict__ bins, int last) {
    __shared__ float sWg[544], sbg[16], sW3[16];
    __shared__ float ws2[16];
    int t = threadIdx.x;
    for (int k = t; k < 544; k += 1024) sWg[k] = (k < 510) ? Wg[k] : 0.0f;
    if (t < 16) { sbg[t] = (t < 15) ? bg[t] : 0.0f; sW3[t] = (t < 15) ? W3[t] : 0.0f; }
    __syncthreads();
    int node = blockIdx.x * 16 + (t >> 6);
    int lane = t & 63, c2 = lane & 7, p = lane >> 3;
    int start = rs[node];
    int deg = re[node] - start;
    const unsigned* hp = (const unsigned*)h_in;            // one h row = 8 uints
    unsigned hsu = hp[(size_t)node * 8 + c2];              // self row pair, hoisted
    float accx = 0.0f, accy = 0.0f;
    for (int base = 0; base < deg; base += 64) {
        int rem = deg - base;
        unsigned ce = 0;
        if (lane < rem) ce = csr[start + base + lane];
        int lim = rem < 64 ? rem : 64;
        unsigned tmp[8];
#pragma unroll
        for (int i = 0; i < 8; i++) {
            int e0 = p + 8 * i;
            unsigned pk = __shfl(ce, e0, 64);
            tmp[i] = (e0 < lim) ? hp[(size_t)(pk & 0x1FFFFu) * 8 + c2] : 0u;
        }
#pragma unroll
        for (int i = 0; i < 8; i++) {
            float2 f = __half22float2(*(__half2*)&tmp[i]);
            accx += f.x;
            accy += f.y;
        }
    }
    // reduce over p-slots (lane bits 3..5); afterwards every lane holds the
    // full channel-pair sums for its c2.
    accx += __shfl_xor(accx, 8, 64);
    accy += __shfl_xor(accy, 8, 64);
    accx += __shfl_xor(accx, 16, 64);
    accy += __shfl_xor(accy, 16, 64);
    accx += __shfl_xor(accx, 32, 64);
    accy += __shfl_xor(accy, 32, 64);
    float dn = dinv[node];
    float2 hsf = __half22float2(*(__half2*)&hsu);
    float avx = fmaxf(dn * (hsf.x + accx) + sbg[2 * c2], 0.0f);        // a[2c2]
    float avy = fmaxf(dn * (hsf.y + accy) + sbg[2 * c2 + 1], 0.0f);    // a[2c2+1]; c2==7 -> ch15 = 0
    if (!last) {
        float ink[16];
#pragma unroll
        for (int j = 0; j < 8; j++) {
            ink[2 * j] = __shfl(avx, j, 64);
            ink[2 * j + 1] = __shfl(avy, j, 64);
        }
        const float4* bp4 = (const float4*)(bb + (size_t)node * 20);
        float4 q0 = bp4[0], q1 = bp4[1], q2 = bp4[2], q3 = bp4[3], q4 = bp4[4];
        float bv[19] = {q0.x, q0.y, q0.z, q0.w, q1.x, q1.y, q1.z, q1.w,
                        q2.x, q2.y, q2.z, q2.w, q3.x, q3.y, q3.z, q3.w,
                        q4.x, q4.y, q4.z};
        int o0 = 2 * c2, o1 = o0 + 1;                       // two output channels per lane
        float s0 = 0.0f, s1 = 0.0f;
#pragma unroll
        for (int k = 0; k < 15; k++) {
            s0 += ink[k] * sWg[o0 * 34 + k];
            s1 += ink[k] * sWg[o1 * 34 + k];                // o1==15 row: zero pad
        }
#pragma unroll
        for (int k = 0; k < 19; k++) {
            s0 += bv[k] * sWg[o0 * 34 + 15 + k];
            s1 += bv[k] * sWg[o1 * 34 + 15 + k];
        }
        if (p == 0)
            ((unsigned*)h_out)[(size_t)node * 8 + c2] = pkh(s0 * dn, s1 * dn);
    } else {
        float c = avx * sW3[2 * c2] + avy * sW3[2 * c2 + 1];   // sW3[15]==0
        c += __shfl_xor(c, 1, 64);
        c += __shfl_xor(c, 2, 64);
        c += __shfl_xor(c, 4, 64);
        if ((t & 63) == 0) ws2[t >> 6] = c;
        __syncthreads();
        if (t == 0) {
            float s = 0.0f;
#pragma unroll
            for (int k = 0; k < 16; k++) s += ws2[k];
            atomicAdd(&bins[blockIdx.x & 63], s);
        }
    }
}

__global__ void k_finalize(const float* __restrict__ bins, const float* __restrict__ b3,
                           float* __restrict__ out) {
    float s = 0.0f;
    for (int k = 0; k < 64; k++) s += bins[k];
    out[0] = tanhf(s * (1.0f / (float)N_NODES) + b3[0]);
}

// ---------------------------------------------------------------------------
extern "C" void kernel_launch(void* const* d_in, const int* in_sizes, int n_in,
                              void* d_out, int out_size, void* d_ws, size_t ws_size,
                              hipStream_t stream) {
    const float* x1 = (const float*)d_in[0];
    const float* x2 = (const float*)d_in[1];
    const int* edges = (const int*)d_in[2];
    const float* W1 = (const float*)d_in[3];
    const float* b1 = (const float*)d_in[4];
    const float* Wg = (const float*)d_in[5];
    const float* bg = (const float*)d_in[6];
    const float* W3 = (const float*)d_in[7];
    const float* b3 = (const float*)d_in[8];
    const float* W4 = (const float*)d_in[9];
    const float* b4 = (const float*)d_in[10];

    const int* row = edges;             // edges[0]
    const int* col = edges + N_EDGES;   // edges[1]

    // workspace layout — ~30 MB (h0/h1 fp16: 3.2 MB each).
    char* ws = (char*)d_ws;
    unsigned* csr  = (unsigned*)ws;                              // NBKT*CAPB  (14.81 MB)
    float*    bb   = (float*)(csr + (size_t)NBKT * CAPB);        // N*20 f32   (8.0 MB)
    __half*   h0   = (__half*)(bb + (size_t)N_NODES * 20);       // N*16 fp16  (3.2 MB)
    __half*   h1   = h0 + (size_t)N_NODES * 16;                  // N*16 fp16  (3.2 MB)
    float*    dinv = (float*)(h1 + (size_t)N_NODES * 16);        // N
    int*      rs   = (int*)(dinv + N_NODES);                     // N
    int*      re   = rs + N_NODES;                               // N
    int*      gcur = re + N_NODES;                               // NBKT
    float*    bins = (float*)(gcur + NBKT);                      // 64

    int gN = (N_NODES + 255) / 256;                              // 391
    int gE = (N_EDGES + 8191) / 8192;                            // 391

    k_initg<<<1, 512, 0, stream>>>(gcur, bins);
    k_bucket<<<gE, 256, 0, stream>>>(row, col, gcur, csr);
    k_sort<<<NBKT, 256, 0, stream>>>(gcur, csr, rs, re, dinv);
    k_ab_h<<<gN, 256, 0, stream>>>(x1, x2, W1, b1, W4, b4, Wg, W3, dinv, bb, h0, bins);
    for (int t = 0; t < 5; t++) {
        const __half* hi = (t & 1) ? h1 : h0;
        __half* ho = (t & 1) ? h0 : h1;
        k_gather<<<N_NODES / 16, 1024, 0, stream>>>(rs, re, csr, hi, dinv, bb, Wg, bg, W3,
                                                    ho, bins, t == 4 ? 1 : 0);
    }
    k_finalize<<<1, 1, 0, stream>>>(bins, b3, (float*)d_out);
}

// Round 4
// 422.090 us; speedup vs baseline: 1.7116x; 1.0894x over previous
//
#include <hip/hip_runtime.h>
#include <hip/hip_fp16.h>
#include <math.h>

#define N_NODES 100000
#define N_BASE  5000
#define N_EDGES 3200000
#define NBKT    391       // dest buckets of 256 nodes
#define CAPB    9472      // csr slots per bucket (mean 8184, sigma 90 -> +14 sigma)
#define EPB     2048      // edges per k_bucket block (4x grid for latency hiding)
#define GEB     1563      // ceil(N_EDGES / EPB)

__device__ inline unsigned pkh(float a, float b) {
    return (unsigned)__half_as_ushort(__float2half_rn(a)) |
           ((unsigned)__half_as_ushort(__float2half_rn(b)) << 16);
}

// ---------------------------------------------------------------------------
// k_initg: gcur[b] = b*CAPB, bins = 0
// ---------------------------------------------------------------------------
__global__ __launch_bounds__(512) void k_initg(int* __restrict__ gcur, float* __restrict__ bins) {
    int t = threadIdx.x;
    if (t < NBKT) gcur[t] = t * CAPB;
    if (t < 64) bins[t] = 0.0f;
}

// ---------------------------------------------------------------------------
// k_bucket (phase A): 1563 blocks x 2048 edges. Edges staged in LDS on the
// first (and only) global read; the scatter loop runs from LDS.
// ---------------------------------------------------------------------------
__global__ __launch_bounds__(256) void k_bucket(const int* __restrict__ row, const int* __restrict__ col,
                                                int* __restrict__ gcur, unsigned* __restrict__ csr) {
    __shared__ int hist[NBKT], gbase[NBKT], cur[NBKT];
    __shared__ int sc[512];
    __shared__ unsigned sedge[EPB];    // packed (d&255)<<17 | src
    __shared__ short sbkt[EPB];        // bucket id (< 391)
    int t = threadIdx.x;
    int e0 = blockIdx.x * EPB;
    int cnt = (N_EDGES - e0 < EPB) ? (N_EDGES - e0) : EPB;
    for (int k = t; k < NBKT; k += 256) hist[k] = 0;
    __syncthreads();
    for (int j = t; j < cnt; j += 256) {
        int d = col[e0 + j];
        int s = row[e0 + j];
        sedge[j] = ((unsigned)(d & 255) << 17) | (unsigned)s;
        sbkt[j] = (short)(d >> 8);
        atomicAdd(&hist[d >> 8], 1);
    }
    __syncthreads();
    // inclusive Hillis scan over 512 slots, 2 per thread
    sc[t] = (t < NBKT) ? hist[t] : 0;
    sc[t + 256] = (t + 256 < NBKT) ? hist[t + 256] : 0;
    __syncthreads();
    for (int off = 1; off < 512; off <<= 1) {
        int v0 = (t >= off) ? sc[t - off] : 0;
        int v1 = sc[t + 256 - off];          // t+256-off >= 0 since off <= 256
        __syncthreads();
        sc[t] += v0;
        sc[t + 256] += v1;
        __syncthreads();
    }
    for (int s = t; s < NBKT; s += 256) {
        cur[s] = sc[s] - hist[s];            // local exclusive offset
        gbase[s] = (hist[s] > 0) ? atomicAdd(&gcur[s], hist[s]) : 0;
    }
    __syncthreads();
    for (int j = t; j < cnt; j += 256) {
        int b = sbkt[j];
        int slot = atomicAdd(&cur[b], 1);
        int local = slot - (sc[b] - hist[b]);
        csr[gbase[b] + local] = sedge[j];
    }
}

// ---------------------------------------------------------------------------
// k_sort (phase B): one block per bucket, 1024 threads (16 waves/block).
// LDS counting sort of <= CAPB edges by local dest; coalesced write-back of
// pure-src csr; emits rs/re and dinv.
// ---------------------------------------------------------------------------
__global__ __launch_bounds__(1024) void k_sort(const int* __restrict__ gcur, unsigned* __restrict__ csr,
                                               int* __restrict__ rs, int* __restrict__ re,
                                               float* __restrict__ dinv) {
    __shared__ unsigned stage[CAPB];
    __shared__ int hist[256], offs[256], cur[256];
    int t = threadIdx.x, b = blockIdx.x;
    int base = b * CAPB;
    int cnt = gcur[b] - base;
    if (t < 256) hist[t] = 0;
    for (int j = t; j < cnt; j += 1024) stage[j] = csr[base + j];
    __syncthreads();
    for (int j = t; j < cnt; j += 1024) atomicAdd(&hist[stage[j] >> 17], 1);
    __syncthreads();
    if (t < 256) offs[t] = hist[t];
    __syncthreads();
    for (int off = 1; off < 256; off <<= 1) {
        int v = 0;
        if (t < 256 && t >= off) v = offs[t - off];
        __syncthreads();
        if (t < 256) offs[t] += v;
        __syncthreads();
    }
    if (t < 256) {
        int excl = offs[t] - hist[t];
        cur[t] = excl;
        int node = b * 256 + t;
        if (node < N_NODES) {
            rs[node] = base + excl;
            re[node] = base + excl + hist[t];
            dinv[node] = rsqrtf((float)(hist[t] + 1));   // +1 self loop
        }
    }
    __syncthreads();
    for (int j = t; j < cnt; j += 1024) {
        unsigned p = stage[j];
        int slot = atomicAdd(&cur[p >> 17], 1);
        csr[base + slot] = p & 0x1FFFFu;             // pure src
    }
}

// ---------------------------------------------------------------------------
// k_ab_h: bb = [x1 | tile(x2)] @ W4^T + b4  (float4 stores, f32)
//         h0 = dinv * (Wg @ [relu(x1@W1^T+b1) | bb])   (fp16 stores)
//         bins += W3[15:34].bb   (iteration-invariant output part)
// ---------------------------------------------------------------------------
__global__ __launch_bounds__(256) void k_ab_h(const float* __restrict__ x1, const float* __restrict__ x2,
                                              const float* __restrict__ W1, const float* __restrict__ b1,
                                              const float* __restrict__ W4, const float* __restrict__ b4,
                                              const float* __restrict__ Wg, const float* __restrict__ W3,
                                              const float* __restrict__ dinv,
                                              float* __restrict__ bb, __half* __restrict__ h0,
                                              float* __restrict__ bins) {
    __shared__ float sW1[225], sb1[15], sW4[361], sb4[19], sWg[510], sW3b[19];
    for (int t = threadIdx.x; t < 225; t += 256) sW1[t] = W1[t];
    for (int t = threadIdx.x; t < 361; t += 256) sW4[t] = W4[t];
    for (int t = threadIdx.x; t < 510; t += 256) sWg[t] = Wg[t];
    if (threadIdx.x < 15) sb1[threadIdx.x] = b1[threadIdx.x];
    if (threadIdx.x < 19) { sb4[threadIdx.x] = b4[threadIdx.x]; sW3b[threadIdx.x] = W3[15 + threadIdx.x]; }
    __syncthreads();
    int i = blockIdx.x * 256 + threadIdx.x;
    bool valid = i < N_NODES;
    int ii = valid ? i : 0;
    float x[15];
#pragma unroll
    for (int k = 0; k < 15; k++) x[k] = x1[(size_t)ii * 15 + k];
    float xt[4];
    int ib = ii % N_BASE;
#pragma unroll
    for (int k = 0; k < 4; k++) xt[k] = x2[(size_t)ib * 4 + k];
    float in[34];
    float bp = 0.0f;
#pragma unroll
    for (int o = 0; o < 19; o++) {
        float s = sb4[o];
#pragma unroll
        for (int k = 0; k < 15; k++) s += x[k] * sW4[o * 19 + k];
#pragma unroll
        for (int k = 0; k < 4; k++) s += xt[k] * sW4[o * 19 + 15 + k];
        in[15 + o] = s;
        bp += s * sW3b[o];
    }
#pragma unroll
    for (int o = 0; o < 15; o++) {
        float s = sb1[o];
#pragma unroll
        for (int k = 0; k < 15; k++) s += x[k] * sW1[o * 15 + k];
        in[o] = fmaxf(s, 0.0f);
    }
    float dn = dinv[ii];
    if (valid) {
        float4* bbp = (float4*)(bb + (size_t)ii * 20);
        bbp[0] = make_float4(in[15], in[16], in[17], in[18]);
        bbp[1] = make_float4(in[19], in[20], in[21], in[22]);
        bbp[2] = make_float4(in[23], in[24], in[25], in[26]);
        bbp[3] = make_float4(in[27], in[28], in[29], in[30]);
        bbp[4] = make_float4(in[31], in[32], in[33], 0.0f);   // [19] pad, never consumed
        float hv[15];
#pragma unroll
        for (int o = 0; o < 15; o++) {
            float s = 0.0f;
#pragma unroll
            for (int k = 0; k < 34; k++) s += in[k] * sWg[o * 34 + k];
            hv[o] = s * dn;
        }
        unsigned hu[8];
#pragma unroll
        for (int k = 0; k < 7; k++) hu[k] = pkh(hv[2 * k], hv[2 * k + 1]);
        hu[7] = pkh(hv[14], 0.0f);                            // ch 15 pad, always 0
        uint4* hp = (uint4*)(h0 + (size_t)ii * 16);
        hp[0] = make_uint4(hu[0], hu[1], hu[2], hu[3]);
        hp[1] = make_uint4(hu[4], hu[5], hu[6], hu[7]);
    }
    float val = valid ? bp : 0.0f;
#pragma unroll
    for (int off = 32; off > 0; off >>= 1) val += __shfl_down(val, off, 64);
    __shared__ float wsum[4];
    if ((threadIdx.x & 63) == 0) wsum[threadIdx.x >> 6] = val;
    __syncthreads();
    if (threadIdx.x == 0) atomicAdd(&bins[blockIdx.x & 63], wsum[0] + wsum[1] + wsum[2] + wsum[3]);
}

// ---------------------------------------------------------------------------
// k_gather: gather loop unchanged (fp16 h, dword/lane, proven). k-split
// epilogue FIXED: the round-2 bug was __shfl(asel, k>>1) -- a shfl returns
// the SOURCE lane's operand, and all source lanes (0..7) have p=0, so odd-k
// terms read avx (wrong channel). Now both avx and avy are shfl'd by ALL
// lanes (uniform exec), then the reader selects by its own parity.
// Only i=0,1 can have k<15 -> 4 shfls total; i>=2 terms are bb loads.
// ---------------------------------------------------------------------------
__global__ __launch_bounds__(1024) void k_gather(const int* __restrict__ rs, const int* __restrict__ re,
                                                 const unsigned* __restrict__ csr,
                                                 const __half* __restrict__ h_in,
                                                 const float* __restrict__ dinv,
                                                 const float* __restrict__ bb,
                                                 const float* __restrict__ Wg,
                                                 const float* __restrict__ bg,
                                                 const float* __restrict__ W3,
                                                 __half* __restrict__ h_out,
                                                 float* __restrict__ bins, int last) {
    __shared__ float sWg[544], sbg[16], sW3[16];
    __shared__ float ws2[16];
    int t = threadIdx.x;
    for (int k = t; k < 544; k += 1024) sWg[k] = (k < 510) ? Wg[k] : 0.0f;
    if (t < 16) { sbg[t] = (t < 15) ? bg[t] : 0.0f; sW3[t] = (t < 15) ? W3[t] : 0.0f; }
    __syncthreads();
    int node = blockIdx.x * 16 + (t >> 6);
    int lane = t & 63, c2 = lane & 7, p = lane >> 3;
    int start = rs[node];
    int deg = re[node] - start;
    const unsigned* hp = (const unsigned*)h_in;            // one h row = 8 uints
    unsigned hsu = hp[(size_t)node * 8 + c2];              // self row pair, hoisted
    float accx = 0.0f, accy = 0.0f;
    for (int base = 0; base < deg; base += 64) {
        int rem = deg - base;
        unsigned ce = 0;
        if (lane < rem) ce = csr[start + base + lane];
        int lim = rem < 64 ? rem : 64;
        unsigned tmp[8];
#pragma unroll
        for (int i = 0; i < 8; i++) {
            int e0 = p + 8 * i;
            unsigned pk = __shfl(ce, e0, 64);
            tmp[i] = (e0 < lim) ? hp[(size_t)(pk & 0x1FFFFu) * 8 + c2] : 0u;
        }
#pragma unroll
        for (int i = 0; i < 8; i++) {
            float2 f = __half22float2(*(__half2*)&tmp[i]);
            accx += f.x;
            accy += f.y;
        }
    }
    // reduce over p-slots (lane bits 3..5); afterwards EVERY lane holds the
    // full channel-pair sums for its c2.
    accx += __shfl_xor(accx, 8, 64);
    accy += __shfl_xor(accy, 8, 64);
    accx += __shfl_xor(accx, 16, 64);
    accy += __shfl_xor(accy, 16, 64);
    accx += __shfl_xor(accx, 32, 64);
    accy += __shfl_xor(accy, 32, 64);
    float dn = dinv[node];
    float2 hsf = __half22float2(*(__half2*)&hsu);
    float avx = fmaxf(dn * (hsf.x + accx) + sbg[2 * c2], 0.0f);        // a[2c2]
    float avy = fmaxf(dn * (hsf.y + accy) + sbg[2 * c2 + 1], 0.0f);    // a[2c2+1]; c2==7 -> ch15 = 0
    if (!last) {
        int o0 = 2 * c2;
        // k = p + 8*i.  a[k] (k<15) lives on lane k>>1: avx if k even, avy if
        // k odd; parity(k) == parity(p).  All 4 shfls run with full exec.
        float ix0 = __shfl(avx, p >> 1, 64);               // k0 = p  (always < 15)
        float iy0 = __shfl(avy, p >> 1, 64);
        float ix1 = __shfl(avx, (p + 8) >> 1, 64);         // k1 = p+8 (<15 unless p==7)
        float iy1 = __shfl(avy, (p + 8) >> 1, 64);
        float inv0 = (p & 1) ? iy0 : ix0;
        float inv1 = (p & 1) ? iy1 : ix1;
        if (p == 7) inv1 = bb[(size_t)node * 20 + 0];      // k1==15 -> in[15] = bb[0]
        float s0 = inv0 * sWg[o0 * 34 + p]       + inv1 * sWg[o0 * 34 + p + 8];
        float s1 = inv0 * sWg[(o0 + 1) * 34 + p] + inv1 * sWg[(o0 + 1) * 34 + p + 8];
#pragma unroll
        for (int i = 2; i < 5; i++) {
            int k = p + 8 * i;
            if (k < 34) {
                float inv = bb[(size_t)node * 20 + (k - 15)];
                s0 += inv * sWg[o0 * 34 + k];
                s1 += inv * sWg[(o0 + 1) * 34 + k];        // o0+1==15 row: zero pad
            }
        }
        s0 += __shfl_xor(s0, 8, 64);
        s1 += __shfl_xor(s1, 8, 64);
        s0 += __shfl_xor(s0, 16, 64);
        s1 += __shfl_xor(s1, 16, 64);
        s0 += __shfl_xor(s0, 32, 64);
        s1 += __shfl_xor(s1, 32, 64);
        if (p == 0)
            ((unsigned*)h_out)[(size_t)node * 8 + c2] = pkh(s0 * dn, s1 * dn);
    } else {
        float c = avx * sW3[2 * c2] + avy * sW3[2 * c2 + 1];   // sW3[15]==0
        c += __shfl_xor(c, 1, 64);
        c += __shfl_xor(c, 2, 64);
        c += __shfl_xor(c, 4, 64);
        if ((t & 63) == 0) ws2[t >> 6] = c;
        __syncthreads();
        if (t == 0) {
            float s = 0.0f;
#pragma unroll
            for (int k = 0; k < 16; k++) s += ws2[k];
            atomicAdd(&bins[blockIdx.x & 63], s);
        }
    }
}

__global__ void k_finalize(const float* __restrict__ bins, const float* __restrict__ b3,
                           float* __restrict__ out) {
    float s = 0.0f;
    for (int k = 0; k < 64; k++) s += bins[k];
    out[0] = tanhf(s * (1.0f / (float)N_NODES) + b3[0]);
}

// ---------------------------------------------------------------------------
extern "C" void kernel_launch(void* const* d_in, const int* in_sizes, int n_in,
                              void* d_out, int out_size, void* d_ws, size_t ws_size,
                              hipStream_t stream) {
    const float* x1 = (const float*)d_in[0];
    const float* x2 = (const float*)d_in[1];
    const int* edges = (const int*)d_in[2];
    const float* W1 = (const float*)d_in[3];
    const float* b1 = (const float*)d_in[4];
    const float* Wg = (const float*)d_in[5];
    const float* bg = (const float*)d_in[6];
    const float* W3 = (const float*)d_in[7];
    const float* b3 = (const float*)d_in[8];
    const float* W4 = (const float*)d_in[9];
    const float* b4 = (const float*)d_in[10];

    const int* row = edges;             // edges[0]
    const int* col = edges + N_EDGES;   // edges[1]

    // workspace layout — ~30 MB (h0/h1 fp16: 3.2 MB each).
    char* ws = (char*)d_ws;
    unsigned* csr  = (unsigned*)ws;                              // NBKT*CAPB  (14.81 MB)
    float*    bb   = (float*)(csr + (size_t)NBKT * CAPB);        // N*20 f32   (8.0 MB)
    __half*   h0   = (__half*)(bb + (size_t)N_NODES * 20);       // N*16 fp16  (3.2 MB)
    __half*   h1   = h0 + (size_t)N_NODES * 16;                  // N*16 fp16  (3.2 MB)
    float*    dinv = (float*)(h1 + (size_t)N_NODES * 16);        // N
    int*      rs   = (int*)(dinv + N_NODES);                     // N
    int*      re   = rs + N_NODES;                               // N
    int*      gcur = re + N_NODES;                               // NBKT
    float*    bins = (float*)(gcur + NBKT);                      // 64

    int gN = (N_NODES + 255) / 256;                              // 391

    k_initg<<<1, 512, 0, stream>>>(gcur, bins);
    k_bucket<<<GEB, 256, 0, stream>>>(row, col, gcur, csr);
    k_sort<<<NBKT, 1024, 0, stream>>>(gcur, csr, rs, re, dinv);
    k_ab_h<<<gN, 256, 0, stream>>>(x1, x2, W1, b1, W4, b4, Wg, W3, dinv, bb, h0, bins);
    for (int t = 0; t < 5; t++) {
        const __half* hi = (t & 1) ? h1 : h0;
        __half* ho = (t & 1) ? h0 : h1;
        k_gather<<<N_NODES / 16, 1024, 0, stream>>>(rs, re, csr, hi, dinv, bb, Wg, bg, W3,
                                                    ho, bins, t == 4 ? 1 : 0);
    }
    k_finalize<<<1, 1, 0, stream>>>(bins, b3, (float*)d_out);
}

// Round 5
// 389.183 us; speedup vs baseline: 1.8563x; 1.0846x over previous
//
#include <hip/hip_runtime.h>
#include <hip/hip_fp16.h>
#include <math.h>

#define N_NODES 100000
#define N_BASE  5000
#define N_EDGES 3200000
#define NBKT    391       // dest buckets of 256 nodes
#define CAPB    9472      // csr slots per bucket (mean 8184, sigma 90 -> +14 sigma)
#define EPB     4096      // edges per k_bucket block
#define GEB     782       // ceil(N_EDGES / EPB)

__device__ inline unsigned pkh(float a, float b) {
    return (unsigned)__half_as_ushort(__float2half_rn(a)) |
           ((unsigned)__half_as_ushort(__float2half_rn(b)) << 16);
}

// ---------------------------------------------------------------------------
// k_initg: gcur[b] = b*CAPB, bins = 0
// ---------------------------------------------------------------------------
__global__ __launch_bounds__(512) void k_initg(int* __restrict__ gcur, float* __restrict__ bins) {
    int t = threadIdx.x;
    if (t < NBKT) gcur[t] = t * CAPB;
    if (t < 64) bins[t] = 0.0f;
}

// ---------------------------------------------------------------------------
// k_bucket (round 4 rewrite): 782 blocks x 4096 edges x 512 threads.
// Theory: the old scatter loop issued 3.2M per-lane random dword stores over
// the whole 14.8MB csr (64 lines per wave-store) -- time was invariant under
// 4x occupancy and 4x atomic count, fingering write transactions as the
// floor. Now edges are placed into LDS sorted by bucket position (pos =
// excl[b]+slot) along with their final global address, and the global write
// loop is LINEAR in pos: addresses are consecutive within each bucket run.
// Pass 2 re-reads col/row (L2-warm) so LDS fits in ~40KB -> 3 blocks/CU.
// ---------------------------------------------------------------------------
__global__ __launch_bounds__(512) void k_bucket(const int* __restrict__ row, const int* __restrict__ col,
                                                int* __restrict__ gcur, unsigned* __restrict__ csr) {
    __shared__ int hist[NBKT], gbase[NBKT], curi[NBKT], excl[NBKT];
    __shared__ int sc[512];
    __shared__ unsigned sdst[EPB];     // packed (d&255)<<17 | src, sorted by bucket
    __shared__ int sadr[EPB];          // final global csr address per slot
    int t = threadIdx.x;
    int e0 = blockIdx.x * EPB;
    int cnt = (N_EDGES - e0 < EPB) ? (N_EDGES - e0) : EPB;
    for (int k = t; k < NBKT; k += 512) hist[k] = 0;
    __syncthreads();
    for (int j = t; j < cnt; j += 512) atomicAdd(&hist[col[e0 + j] >> 8], 1);
    __syncthreads();
    sc[t] = (t < NBKT) ? hist[t] : 0;
    __syncthreads();
    for (int off = 1; off < 512; off <<= 1) {
        int v = (t >= off) ? sc[t - off] : 0;
        __syncthreads();
        sc[t] += v;
        __syncthreads();
    }
    if (t < NBKT) {
        int e = sc[t] - hist[t];
        excl[t] = e;
        curi[t] = e;
        gbase[t] = (hist[t] > 0) ? atomicAdd(&gcur[t], hist[t]) : 0;
    }
    __syncthreads();
    for (int j = t; j < cnt; j += 512) {
        int d = col[e0 + j];           // L2-warm re-read
        int s = row[e0 + j];
        int b = d >> 8;
        int pos = atomicAdd(&curi[b], 1);              // pos in [excl[b], excl[b]+hist[b])
        sdst[pos] = ((unsigned)(d & 255) << 17) | (unsigned)s;
        sadr[pos] = gbase[b] + (pos - excl[b]);
    }
    __syncthreads();
    for (int j = t; j < cnt; j += 512) csr[sadr[j]] = sdst[j];   // run-linear writes
}

// ---------------------------------------------------------------------------
// k_sort (phase B): one block per bucket, 1024 threads (16 waves/block).
// LDS counting sort of <= CAPB edges by local dest; coalesced write-back of
// pure-src csr; emits rs/re and dinv.
// ---------------------------------------------------------------------------
__global__ __launch_bounds__(1024) void k_sort(const int* __restrict__ gcur, unsigned* __restrict__ csr,
                                               int* __restrict__ rs, int* __restrict__ re,
                                               float* __restrict__ dinv) {
    __shared__ unsigned stage[CAPB];
    __shared__ int hist[256], offs[256], cur[256];
    int t = threadIdx.x, b = blockIdx.x;
    int base = b * CAPB;
    int cnt = gcur[b] - base;
    if (t < 256) hist[t] = 0;
    for (int j = t; j < cnt; j += 1024) stage[j] = csr[base + j];
    __syncthreads();
    for (int j = t; j < cnt; j += 1024) atomicAdd(&hist[stage[j] >> 17], 1);
    __syncthreads();
    if (t < 256) offs[t] = hist[t];
    __syncthreads();
    for (int off = 1; off < 256; off <<= 1) {
        int v = 0;
        if (t < 256 && t >= off) v = offs[t - off];
        __syncthreads();
        if (t < 256) offs[t] += v;
        __syncthreads();
    }
    if (t < 256) {
        int excl = offs[t] - hist[t];
        cur[t] = excl;
        int node = b * 256 + t;
        if (node < N_NODES) {
            rs[node] = base + excl;
            re[node] = base + excl + hist[t];
            dinv[node] = rsqrtf((float)(hist[t] + 1));   // +1 self loop
        }
    }
    __syncthreads();
    for (int j = t; j < cnt; j += 1024) {
        unsigned p = stage[j];
        int slot = atomicAdd(&cur[p >> 17], 1);
        csr[base + slot] = p & 0x1FFFFu;             // pure src
    }
}

// ---------------------------------------------------------------------------
// k_ab_h: bb = [x1 | tile(x2)] @ W4^T + b4  (float4 stores, f32)
//         h0 = dinv * (Wg @ [relu(x1@W1^T+b1) | bb])   (fp16 stores)
//         bins += W3[15:34].bb   (iteration-invariant output part)
// ---------------------------------------------------------------------------
__global__ __launch_bounds__(256) void k_ab_h(const float* __restrict__ x1, const float* __restrict__ x2,
                                              const float* __restrict__ W1, const float* __restrict__ b1,
                                              const float* __restrict__ W4, const float* __restrict__ b4,
                                              const float* __restrict__ Wg, const float* __restrict__ W3,
                                              const float* __restrict__ dinv,
                                              float* __restrict__ bb, __half* __restrict__ h0,
                                              float* __restrict__ bins) {
    __shared__ float sW1[225], sb1[15], sW4[361], sb4[19], sWg[510], sW3b[19];
    for (int t = threadIdx.x; t < 225; t += 256) sW1[t] = W1[t];
    for (int t = threadIdx.x; t < 361; t += 256) sW4[t] = W4[t];
    for (int t = threadIdx.x; t < 510; t += 256) sWg[t] = Wg[t];
    if (threadIdx.x < 15) sb1[threadIdx.x] = b1[threadIdx.x];
    if (threadIdx.x < 19) { sb4[threadIdx.x] = b4[threadIdx.x]; sW3b[threadIdx.x] = W3[15 + threadIdx.x]; }
    __syncthreads();
    int i = blockIdx.x * 256 + threadIdx.x;
    bool valid = i < N_NODES;
    int ii = valid ? i : 0;
    float x[15];
#pragma unroll
    for (int k = 0; k < 15; k++) x[k] = x1[(size_t)ii * 15 + k];
    float xt[4];
    int ib = ii % N_BASE;
#pragma unroll
    for (int k = 0; k < 4; k++) xt[k] = x2[(size_t)ib * 4 + k];
    float in[34];
    float bp = 0.0f;
#pragma unroll
    for (int o = 0; o < 19; o++) {
        float s = sb4[o];
#pragma unroll
        for (int k = 0; k < 15; k++) s += x[k] * sW4[o * 19 + k];
#pragma unroll
        for (int k = 0; k < 4; k++) s += xt[k] * sW4[o * 19 + 15 + k];
        in[15 + o] = s;
        bp += s * sW3b[o];
    }
#pragma unroll
    for (int o = 0; o < 15; o++) {
        float s = sb1[o];
#pragma unroll
        for (int k = 0; k < 15; k++) s += x[k] * sW1[o * 15 + k];
        in[o] = fmaxf(s, 0.0f);
    }
    float dn = dinv[ii];
    if (valid) {
        float4* bbp = (float4*)(bb + (size_t)ii * 20);
        bbp[0] = make_float4(in[15], in[16], in[17], in[18]);
        bbp[1] = make_float4(in[19], in[20], in[21], in[22]);
        bbp[2] = make_float4(in[23], in[24], in[25], in[26]);
        bbp[3] = make_float4(in[27], in[28], in[29], in[30]);
        bbp[4] = make_float4(in[31], in[32], in[33], 0.0f);   // [19] pad, never consumed
        float hv[15];
#pragma unroll
        for (int o = 0; o < 15; o++) {
            float s = 0.0f;
#pragma unroll
            for (int k = 0; k < 34; k++) s += in[k] * sWg[o * 34 + k];
            hv[o] = s * dn;
        }
        unsigned hu[8];
#pragma unroll
        for (int k = 0; k < 7; k++) hu[k] = pkh(hv[2 * k], hv[2 * k + 1]);
        hu[7] = pkh(hv[14], 0.0f);                            // ch 15 pad, always 0
        uint4* hp = (uint4*)(h0 + (size_t)ii * 16);
        hp[0] = make_uint4(hu[0], hu[1], hu[2], hu[3]);
        hp[1] = make_uint4(hu[4], hu[5], hu[6], hu[7]);
    }
    float val = valid ? bp : 0.0f;
#pragma unroll
    for (int off = 32; off > 0; off >>= 1) val += __shfl_down(val, off, 64);
    __shared__ float wsum[4];
    if ((threadIdx.x & 63) == 0) wsum[threadIdx.x >> 6] = val;
    __syncthreads();
    if (threadIdx.x == 0) atomicAdd(&bins[blockIdx.x & 63], wsum[0] + wsum[1] + wsum[2] + wsum[3]);
}

// ---------------------------------------------------------------------------
// k_gather (unchanged from round 3's verified version): fp16 h, dword/lane
// gather, k-split epilogue with parity-correct shfls.
// ---------------------------------------------------------------------------
__global__ __launch_bounds__(1024) void k_gather(const int* __restrict__ rs, const int* __restrict__ re,
                                                 const unsigned* __restrict__ csr,
                                                 const __half* __restrict__ h_in,
                                                 const float* __restrict__ dinv,
                                                 const float* __restrict__ bb,
                                                 const float* __restrict__ Wg,
                                                 const float* __restrict__ bg,
                                                 const float* __restrict__ W3,
                                                 __half* __restrict__ h_out,
                                                 float* __restrict__ bins, int last) {
    __shared__ float sWg[544], sbg[16], sW3[16];
    __shared__ float ws2[16];
    int t = threadIdx.x;
    for (int k = t; k < 544; k += 1024) sWg[k] = (k < 510) ? Wg[k] : 0.0f;
    if (t < 16) { sbg[t] = (t < 15) ? bg[t] : 0.0f; sW3[t] = (t < 15) ? W3[t] : 0.0f; }
    __syncthreads();
    int node = blockIdx.x * 16 + (t >> 6);
    int lane = t & 63, c2 = lane & 7, p = lane >> 3;
    int start = rs[node];
    int deg = re[node] - start;
    const unsigned* hp = (const unsigned*)h_in;            // one h row = 8 uints
    unsigned hsu = hp[(size_t)node * 8 + c2];              // self row pair, hoisted
    float accx = 0.0f, accy = 0.0f;
    for (int base = 0; base < deg; base += 64) {
        int rem = deg - base;
        unsigned ce = 0;
        if (lane < rem) ce = csr[start + base + lane];
        int lim = rem < 64 ? rem : 64;
        unsigned tmp[8];
#pragma unroll
        for (int i = 0; i < 8; i++) {
            int e0 = p + 8 * i;
            unsigned pk = __shfl(ce, e0, 64);
            tmp[i] = (e0 < lim) ? hp[(size_t)(pk & 0x1FFFFu) * 8 + c2] : 0u;
        }
#pragma unroll
        for (int i = 0; i < 8; i++) {
            float2 f = __half22float2(*(__half2*)&tmp[i]);
            accx += f.x;
            accy += f.y;
        }
    }
    // reduce over p-slots (lane bits 3..5); afterwards EVERY lane holds the
    // full channel-pair sums for its c2.
    accx += __shfl_xor(accx, 8, 64);
    accy += __shfl_xor(accy, 8, 64);
    accx += __shfl_xor(accx, 16, 64);
    accy += __shfl_xor(accy, 16, 64);
    accx += __shfl_xor(accx, 32, 64);
    accy += __shfl_xor(accy, 32, 64);
    float dn = dinv[node];
    float2 hsf = __half22float2(*(__half2*)&hsu);
    float avx = fmaxf(dn * (hsf.x + accx) + sbg[2 * c2], 0.0f);        // a[2c2]
    float avy = fmaxf(dn * (hsf.y + accy) + sbg[2 * c2 + 1], 0.0f);    // a[2c2+1]; c2==7 -> ch15 = 0
    if (!last) {
        int o0 = 2 * c2;
        // k = p + 8*i.  a[k] (k<15) lives on lane k>>1: avx if k even, avy if
        // k odd; parity(k) == parity(p).  All 4 shfls run with full exec.
        float ix0 = __shfl(avx, p >> 1, 64);               // k0 = p  (always < 15)
        float iy0 = __shfl(avy, p >> 1, 64);
        float ix1 = __shfl(avx, (p + 8) >> 1, 64);         // k1 = p+8 (<15 unless p==7)
        float iy1 = __shfl(avy, (p + 8) >> 1, 64);
        float inv0 = (p & 1) ? iy0 : ix0;
        float inv1 = (p & 1) ? iy1 : ix1;
        if (p == 7) inv1 = bb[(size_t)node * 20 + 0];      // k1==15 -> in[15] = bb[0]
        float s0 = inv0 * sWg[o0 * 34 + p]       + inv1 * sWg[o0 * 34 + p + 8];
        float s1 = inv0 * sWg[(o0 + 1) * 34 + p] + inv1 * sWg[(o0 + 1) * 34 + p + 8];
#pragma unroll
        for (int i = 2; i < 5; i++) {
            int k = p + 8 * i;
            if (k < 34) {
                float inv = bb[(size_t)node * 20 + (k - 15)];
                s0 += inv * sWg[o0 * 34 + k];
                s1 += inv * sWg[(o0 + 1) * 34 + k];        // o0+1==15 row: zero pad
            }
        }
        s0 += __shfl_xor(s0, 8, 64);
        s1 += __shfl_xor(s1, 8, 64);
        s0 += __shfl_xor(s0, 16, 64);
        s1 += __shfl_xor(s1, 16, 64);
        s0 += __shfl_xor(s0, 32, 64);
        s1 += __shfl_xor(s1, 32, 64);
        if (p == 0)
            ((unsigned*)h_out)[(size_t)node * 8 + c2] = pkh(s0 * dn, s1 * dn);
    } else {
        float c = avx * sW3[2 * c2] + avy * sW3[2 * c2 + 1];   // sW3[15]==0
        c += __shfl_xor(c, 1, 64);
        c += __shfl_xor(c, 2, 64);
        c += __shfl_xor(c, 4, 64);
        if ((t & 63) == 0) ws2[t >> 6] = c;
        __syncthreads();
        if (t == 0) {
            float s = 0.0f;
#pragma unroll
            for (int k = 0; k < 16; k++) s += ws2[k];
            atomicAdd(&bins[blockIdx.x & 63], s);
        }
    }
}

__global__ void k_finalize(const float* __restrict__ bins, const float* __restrict__ b3,
                           float* __restrict__ out) {
    float s = 0.0f;
    for (int k = 0; k < 64; k++) s += bins[k];
    out[0] = tanhf(s * (1.0f / (float)N_NODES) + b3[0]);
}

// ---------------------------------------------------------------------------
extern "C" void kernel_launch(void* const* d_in, const int* in_sizes, int n_in,
                              void* d_out, int out_size, void* d_ws, size_t ws_size,
                              hipStream_t stream) {
    const float* x1 = (const float*)d_in[0];
    const float* x2 = (const float*)d_in[1];
    const int* edges = (const int*)d_in[2];
    const float* W1 = (const float*)d_in[3];
    const float* b1 = (const float*)d_in[4];
    const float* Wg = (const float*)d_in[5];
    const float* bg = (const float*)d_in[6];
    const float* W3 = (const float*)d_in[7];
    const float* b3 = (const float*)d_in[8];
    const float* W4 = (const float*)d_in[9];
    const float* b4 = (const float*)d_in[10];

    const int* row = edges;             // edges[0]
    const int* col = edges + N_EDGES;   // edges[1]

    // workspace layout — ~30 MB (h0/h1 fp16: 3.2 MB each).
    char* ws = (char*)d_ws;
    unsigned* csr  = (unsigned*)ws;                              // NBKT*CAPB  (14.81 MB)
    float*    bb   = (float*)(csr + (size_t)NBKT * CAPB);        // N*20 f32   (8.0 MB)
    __half*   h0   = (__half*)(bb + (size_t)N_NODES * 20);       // N*16 fp16  (3.2 MB)
    __half*   h1   = h0 + (size_t)N_NODES * 16;                  // N*16 fp16  (3.2 MB)
    float*    dinv = (float*)(h1 + (size_t)N_NODES * 16);        // N
    int*      rs   = (int*)(dinv + N_NODES);                     // N
    int*      re   = rs + N_NODES;                               // N
    int*      gcur = re + N_NODES;                               // NBKT
    float*    bins = (float*)(gcur + NBKT);                      // 64

    int gN = (N_NODES + 255) / 256;                              // 391

    k_initg<<<1, 512, 0, stream>>>(gcur, bins);
    k_bucket<<<GEB, 512, 0, stream>>>(row, col, gcur, csr);
    k_sort<<<NBKT, 1024, 0, stream>>>(gcur, csr, rs, re, dinv);
    k_ab_h<<<gN, 256, 0, stream>>>(x1, x2, W1, b1, W4, b4, Wg, W3, dinv, bb, h0, bins);
    for (int t = 0; t < 5; t++) {
        const __half* hi = (t & 1) ? h1 : h0;
        __half* ho = (t & 1) ? h0 : h1;
        k_gather<<<N_NODES / 16, 1024, 0, stream>>>(rs, re, csr, hi, dinv, bb, Wg, bg, W3,
                                                    ho, bins, t == 4 ? 1 : 0);
    }
    k_finalize<<<1, 1, 0, stream>>>(bins, b3, (float*)d_out);
}